// Round 1
// baseline (882.230 us; speedup 1.0000x reference)
//
#include <hip/hip_runtime.h>

#define D_    128
#define DH_   32
#define ROWS_ 256
#define XS_STRIDE_ 257   // pad: conflict-free transposed LDS tile

// Fused: per-row MLP score -> e=exp(score) -> per-segment weighted accumulation
// out layout: [0, P*128)       = numerator accumulators (atomic)
//             [P*128, P*129)   = denominator accumulators (atomic), later pids
__global__ __launch_bounds__(256, 3) void tap_main(
    const float* __restrict__ x,
    const int*   __restrict__ pid,
    const float* __restrict__ W1,
    const float* __restrict__ b1,
    const float* __restrict__ W2,
    const float* __restrict__ b2,
    float* __restrict__ out,
    int N, int P)
{
    __shared__ float sW1[D_ * DH_];          // 16 KB, W1[k*32 + j]
    __shared__ float sB1[DH_];
    __shared__ float sW2[DH_];
    __shared__ float xs[32 * XS_STRIDE_];    // 32.9 KB, xs[k_local*257 + r]
    __shared__ float se[ROWS_];
    __shared__ int   sid[ROWS_];

    const int tid  = threadIdx.x;
    const int row0 = blockIdx.x * ROWS_;

    // stage W1 (4096 floats = 1024 float4, 4 per thread)
    {
        const float4* w4 = (const float4*)W1;
        float4*       s4 = (float4*)sW1;
        #pragma unroll
        for (int i = 0; i < 4; ++i) s4[tid + 256 * i] = w4[tid + 256 * i];
    }
    if (tid < DH_) { sB1[tid] = b1[tid]; sW2[tid] = W2[tid]; }
    {
        int gr = row0 + tid; if (gr > N - 1) gr = N - 1;
        sid[tid] = pid[gr];
    }
    const float b2v   = b2[0];
    const int   myrow = row0 + tid;
    const bool  valid = myrow < N;

    __syncthreads();   // W1/B1/W2/sid ready

    float h[DH_];
    #pragma unroll
    for (int j = 0; j < DH_; ++j) h[j] = sB1[j];

    // ---- Phase A: h = x_row @ W1 + b1, chunked over k ----
    for (int c = 0; c < 4; ++c) {
        // stage chunk c transposed: rows row0..row0+255, cols c*32..c*32+31
        #pragma unroll
        for (int it = 0; it < 8; ++it) {
            int idx = tid + 256 * it;          // 0..2047 float4s
            int rr  = idx >> 3;                // row within tile
            int cc  = (idx & 7) << 2;          // col within chunk
            int gr  = row0 + rr; if (gr > N - 1) gr = N - 1;
            float4 v = *(const float4*)&x[gr * D_ + c * 32 + cc];
            xs[(cc + 0) * XS_STRIDE_ + rr] = v.x;
            xs[(cc + 1) * XS_STRIDE_ + rr] = v.y;
            xs[(cc + 2) * XS_STRIDE_ + rr] = v.z;
            xs[(cc + 3) * XS_STRIDE_ + rr] = v.w;
        }
        __syncthreads();

        const float* wbase = &sW1[c * 32 * DH_];
        #pragma unroll 4
        for (int k = 0; k < 32; ++k) {
            float xk = xs[k * XS_STRIDE_ + tid];
            const float4* wr = (const float4*)&wbase[k * DH_];
            #pragma unroll
            for (int jj = 0; jj < 8; ++jj) {
                float4 w = wr[jj];
                h[jj * 4 + 0] = fmaf(xk, w.x, h[jj * 4 + 0]);
                h[jj * 4 + 1] = fmaf(xk, w.y, h[jj * 4 + 1]);
                h[jj * 4 + 2] = fmaf(xk, w.z, h[jj * 4 + 2]);
                h[jj * 4 + 3] = fmaf(xk, w.w, h[jj * 4 + 3]);
            }
        }
        __syncthreads();   // before next chunk overwrites xs
    }

    // ---- epilogue: tanh + W2 dot + exp ----
    float s = b2v;
    #pragma unroll
    for (int j = 0; j < DH_; ++j) {
        float hj = h[j];
        hj = fminf(fmaxf(hj, -15.f), 15.f);
        float z = __expf(2.f * hj);          // tanh(x) = 1 - 2/(e^{2x}+1)
        float t = 1.f - 2.f / (z + 1.f);
        s = fmaf(t, sW2[j], s);
    }
    float e = valid ? __expf(s) : 0.f;       // bounded: |s| <= ~6
    se[tid] = e;
    __syncthreads();

    // ---- Phase B: per-wave segment accumulation (64 rows/wave) ----
    const int lane = tid & 63;
    const int rb   = (tid >> 6) << 6;
    float a0 = 0.f, a1 = 0.f, ad = 0.f;
    int   cur = sid[rb];
    for (int r = rb; r < rb + 64; ++r) {
        int sg = sid[r];                      // wave-uniform
        if (sg != cur) {
            atomicAdd(&out[cur * D_ + 2 * lane],     a0);
            atomicAdd(&out[cur * D_ + 2 * lane + 1], a1);
            if (lane == 0) atomicAdd(&out[P * D_ + cur], ad);
            a0 = a1 = ad = 0.f;
            cur = sg;
        }
        float ev = se[r];
        int gr = row0 + r; if (gr > N - 1) gr = N - 1;
        const float2 xv = *(const float2*)&x[gr * D_ + 2 * lane];
        a0 = fmaf(ev, xv.x, a0);
        a1 = fmaf(ev, xv.y, a1);
        ad += ev;
    }
    atomicAdd(&out[cur * D_ + 2 * lane],     a0);
    atomicAdd(&out[cur * D_ + 2 * lane + 1], a1);
    if (lane == 0) atomicAdd(&out[P * D_ + cur], ad);
}

// Divide by denominator (0 -> 1, matches reference guard), then overwrite
// denominator slot with float(pid).
__global__ __launch_bounds__(128) void tap_finalize(float* __restrict__ out, int P)
{
    const int p = blockIdx.x;
    const int f = threadIdx.x;     // 128 threads
    float den = out[P * D_ + p];
    den = (den == 0.f) ? 1.f : den;
    float v = out[p * D_ + f];
    __syncthreads();               // all reads of den slot done before overwrite
    out[p * D_ + f] = v / den;
    if (f == 0) out[P * D_ + p] = (float)p;
}

extern "C" void kernel_launch(void* const* d_in, const int* in_sizes, int n_in,
                              void* d_out, int out_size, void* d_ws, size_t ws_size,
                              hipStream_t stream)
{
    const float* x   = (const float*)d_in[0];
    const int*   pid = (const int*)d_in[1];
    const float* W1  = (const float*)d_in[2];
    const float* b1  = (const float*)d_in[3];
    const float* W2  = (const float*)d_in[4];
    const float* b2  = (const float*)d_in[5];
    float* out = (float*)d_out;

    const int N = in_sizes[0] / D_;          // 1,000,000
    const int P = out_size / (D_ + 1);       // 16,384

    hipMemsetAsync(d_out, 0, (size_t)out_size * sizeof(float), stream);

    const int blocks = (N + ROWS_ - 1) / ROWS_;
    tap_main<<<blocks, 256, 0, stream>>>(x, pid, W1, b1, W2, b2, out, N, P);
    tap_finalize<<<P, 128, 0, stream>>>(out, P);
}

// Round 2
// 752.015 us; speedup vs baseline: 1.1732x; 1.1732x over previous
//
#include <hip/hip_runtime.h>

#define D_  128
#define DH_ 32

typedef __attribute__((ext_vector_type(8))) short bf16x8;  // MFMA A/B frag (4 VGPRs)
typedef __attribute__((ext_vector_type(4))) float f32x4;   // MFMA C/D frag

__device__ __forceinline__ short f2bf(float f) {
    // round-to-nearest-even fp32 -> bf16
    unsigned u = __float_as_uint(f);
    unsigned r = (u + 0x7FFF + ((u >> 16) & 1)) >> 16;
    return (short)r;
}

// Fused: MFMA scores (bf16) -> exp -> per-segment weighted accumulation (fp32).
// out layout: [0, P*128)     = numerator accumulators (atomic)
//             [P*128, P*129) = denominator accumulators (atomic), later pids
__global__ __launch_bounds__(256, 4) void tap_main(
    const float* __restrict__ x,
    const int*   __restrict__ pid,
    const float* __restrict__ W1,
    const float* __restrict__ b1,
    const float* __restrict__ W2,
    const float* __restrict__ b2,
    float* __restrict__ out,
    int N, int P)
{
    __shared__ int   sid[256];
    __shared__ float se[256];

    const int tid  = threadIdx.x;
    const int lane = tid & 63;
    const int wave = tid >> 6;
    const int row0 = blockIdx.x * 256;
    const int rb   = wave * 64;           // wave's row base within block

    // sid: each wave stages its own 64 rows' pids (no cross-wave dep -> no barrier)
    { int gr = row0 + tid; if (gr > N - 1) gr = N - 1; sid[tid] = pid[gr]; }

    const int n16  = lane & 15;           // m (A) / n (B,D col) index
    const int quad = lane >> 4;           // k-group

    // ---- B fragments: W1[k][j], k = kt*32 + quad*8 + i, j = jt*16 + n16 ----
    // (same (quad,i)->k mapping as A frags, so any HW k-permutation cancels)
    bf16x8 bfrag[4][2];
    #pragma unroll
    for (int kt = 0; kt < 4; ++kt)
        #pragma unroll
        for (int jt = 0; jt < 2; ++jt) {
            const float* wp = W1 + (kt * 32 + quad * 8) * DH_ + jt * 16 + n16;
            #pragma unroll
            for (int i = 0; i < 8; ++i) bfrag[kt][jt][i] = f2bf(wp[i * DH_]);
        }

    f32x4 acc[4][2] = {};  // [mt][jt]; D row = quad*4+reg, col = n16

    // ---- K loop: h = x @ W1 via MFMA ----
    for (int kt = 0; kt < 4; ++kt) {
        bf16x8 afrag[4];
        #pragma unroll
        for (int mt = 0; mt < 4; ++mt) {
            int r = row0 + rb + mt * 16 + n16; if (r > N - 1) r = N - 1;
            const float* ap = x + (size_t)r * D_ + kt * 32 + quad * 8;
            float4 v0 = *(const float4*)ap;
            float4 v1 = *(const float4*)(ap + 4);
            afrag[mt][0] = f2bf(v0.x); afrag[mt][1] = f2bf(v0.y);
            afrag[mt][2] = f2bf(v0.z); afrag[mt][3] = f2bf(v0.w);
            afrag[mt][4] = f2bf(v1.x); afrag[mt][5] = f2bf(v1.y);
            afrag[mt][6] = f2bf(v1.z); afrag[mt][7] = f2bf(v1.w);
        }
        #pragma unroll
        for (int mt = 0; mt < 4; ++mt)
            #pragma unroll
            for (int jt = 0; jt < 2; ++jt)
                acc[mt][jt] = __builtin_amdgcn_mfma_f32_16x16x32_bf16(
                    afrag[mt], bfrag[kt][jt], acc[mt][jt], 0, 0, 0);
    }

    // ---- epilogue: s = tanh(h + b1) @ W2 + b2 ; e = exp(s) ----
    const float b2v = b2[0];
    float w2v[2], b1v[2];
    #pragma unroll
    for (int jt = 0; jt < 2; ++jt) {
        w2v[jt] = W2[jt * 16 + n16];
        b1v[jt] = b1[jt * 16 + n16];
    }

    #pragma unroll
    for (int mt = 0; mt < 4; ++mt) {
        #pragma unroll
        for (int q = 0; q < 4; ++q) {
            float s = 0.f;
            #pragma unroll
            for (int jt = 0; jt < 2; ++jt) {
                float h = acc[mt][jt][q] + b1v[jt];
                h = fminf(fmaxf(h, -15.f), 15.f);
                float z = __expf(2.f * h);          // tanh via exp
                float t = 1.f - 2.f / (z + 1.f);
                s = fmaf(t, w2v[jt], s);
            }
            // reduce over the 16 j-lanes (xor masks stay within the quad)
            s += __shfl_xor(s, 1);
            s += __shfl_xor(s, 2);
            s += __shfl_xor(s, 4);
            s += __shfl_xor(s, 8);
            if (n16 == 0) {
                int rloc = rb + mt * 16 + quad * 4 + q;
                int gr   = row0 + rloc;
                se[rloc] = (gr < N) ? __expf(s + b2v) : 0.f;  // bounded |s|<~6
            }
        }
    }
    // se/sid produced and consumed by the same wave -> program order + waitcnt

    // ---- Phase B: per-wave segment accumulation (lane = feature pair) ----
    float a0 = 0.f, a1 = 0.f, ad = 0.f;
    int   cur = sid[rb];
    #pragma unroll
    for (int r = rb; r < rb + 64; ++r) {
        int sg = sid[r];                      // wave-uniform
        if (sg != cur) {
            atomicAdd(&out[cur * D_ + 2 * lane],     a0);
            atomicAdd(&out[cur * D_ + 2 * lane + 1], a1);
            if (lane == 0) atomicAdd(&out[P * D_ + cur], ad);
            a0 = a1 = ad = 0.f;
            cur = sg;
        }
        float ev = se[r];
        int gr = row0 + r; if (gr > N - 1) gr = N - 1;
        const float2 xv = *(const float2*)&x[(size_t)gr * D_ + 2 * lane];
        a0 = fmaf(ev, xv.x, a0);
        a1 = fmaf(ev, xv.y, a1);
        ad += ev;
    }
    atomicAdd(&out[cur * D_ + 2 * lane],     a0);
    atomicAdd(&out[cur * D_ + 2 * lane + 1], a1);
    if (lane == 0) atomicAdd(&out[P * D_ + cur], ad);
}

// Divide by denominator (0 -> 1, matches reference guard), then overwrite
// denominator slot with float(pid).
__global__ __launch_bounds__(128) void tap_finalize(float* __restrict__ out, int P)
{
    const int p = blockIdx.x;
    const int f = threadIdx.x;     // 128 threads
    float den = out[P * D_ + p];
    den = (den == 0.f) ? 1.f : den;
    float v = out[p * D_ + f];
    __syncthreads();               // all reads of den slot done before overwrite
    out[p * D_ + f] = v / den;
    if (f == 0) out[P * D_ + p] = (float)p;
}

extern "C" void kernel_launch(void* const* d_in, const int* in_sizes, int n_in,
                              void* d_out, int out_size, void* d_ws, size_t ws_size,
                              hipStream_t stream)
{
    const float* x   = (const float*)d_in[0];
    const int*   pid = (const int*)d_in[1];
    const float* W1  = (const float*)d_in[2];
    const float* b1  = (const float*)d_in[3];
    const float* W2  = (const float*)d_in[4];
    const float* b2  = (const float*)d_in[5];
    float* out = (float*)d_out;

    const int N = in_sizes[0] / D_;          // 1,000,000
    const int P = out_size / (D_ + 1);       // 16,384

    hipMemsetAsync(d_out, 0, (size_t)out_size * sizeof(float), stream);

    const int blocks = (N + 255) / 256;
    tap_main<<<blocks, 256, 0, stream>>>(x, pid, W1, b1, W2, b2, out, N, P);
    tap_finalize<<<P, 128, 0, stream>>>(out, P);
}